// Round 1
// baseline (357.443 us; speedup 1.0000x reference)
//
#include <hip/hip_runtime.h>
#include <hip/hip_bf16.h>
#include <stdint.h>

typedef unsigned short u16;
typedef short s16x8 __attribute__((ext_vector_type(8)));
typedef float f32x4 __attribute__((ext_vector_type(4)));

#define DIM 256
#define HW  4096
#define NB  8

__device__ __forceinline__ u16 f2bf(float f) {
  union { float f; unsigned u; } v; v.f = f;
  unsigned r = v.u + 0x7FFFu + ((v.u >> 16) & 1u);
  return (u16)(r >> 16);
}

typedef __attribute__((address_space(1))) const void gvoid_c;
typedef __attribute__((address_space(3))) void lvoid;

__device__ __forceinline__ void gload_lds16(const void* g, void* l) {
  __builtin_amdgcn_global_load_lds((gvoid_c*)g, (lvoid*)l, 16, 0, 0);
}

// ---------------- kernel 1: weights f32 -> bf16 ----------------
__global__ void prep_w(const float* __restrict__ Wq, const float* __restrict__ Wk,
                       const float* __restrict__ Wv, u16* __restrict__ dst) {
  int idx = blockIdx.x * 256 + threadIdx.x;   // 0 .. 98303
  float v;
  if (idx < 16384)        v = Wq[idx];
  else if (idx < 32768)   v = Wk[idx - 16384];
  else                    v = Wv[idx - 32768];
  dst[idx] = f2bf(v);
}

// ---------------- kernel 2: QKV projections (MFMA) ----------------
// Q,K stored [B][N][64] (d contiguous); V stored [B][256][N] (n contiguous)
__global__ __launch_bounds__(256) void proj_qkv(
    const float* __restrict__ sem, const float* __restrict__ foren,
    const u16* __restrict__ Wqb, const u16* __restrict__ Wkb, const u16* __restrict__ Wvb,
    const float* __restrict__ bq, const float* __restrict__ bk, const float* __restrict__ bv,
    u16* __restrict__ Qo, u16* __restrict__ Ko, u16* __restrict__ Vo) {
  __shared__ u16 lds[32768];  // [0:16384) sem^T [px][256], [16384:32768) foren^T
  const int t  = threadIdx.x;
  const int b  = blockIdx.x & 7;
  const int n0 = (blockIdx.x >> 3) * 64;
  // ---- load + transpose X into LDS (bf16, XOR-swizzled) ----
  {
    const int px  = t & 63;
    const int cb  = (t >> 6) * 8;
    const int swz = (px & 31) * 8;
    for (int i = 0; i < 8; ++i) {
      int c0 = i * 32 + cb;
      size_t gb = ((size_t)b * DIM + c0) * HW + n0 + px;
      s16x8 us, uf;
#pragma unroll
      for (int j = 0; j < 8; ++j) {
        us[j] = (short)f2bf(sem[gb + (size_t)j * HW]);
        uf[j] = (short)f2bf(foren[gb + (size_t)j * HW]);
      }
      int li = px * 256 + (c0 ^ swz);
      *(s16x8*)(lds + li)         = us;
      *(s16x8*)(lds + 16384 + li) = uf;
    }
  }
  __syncthreads();
  const int w = t >> 6, lane = t & 63, ln = lane & 15, g = lane >> 4;

  // ---- Q = mfma(semT, WqT): D rows = px ----
  {
    int r = w * 16 + ln;
    s16x8 a[8];
#pragma unroll
    for (int kc = 0; kc < 8; ++kc)
      a[kc] = *(const s16x8*)(lds + r * 256 + ((kc * 32 + g * 8) ^ ((r & 31) * 8)));
#pragma unroll
    for (int ct = 0; ct < 4; ++ct) {
      int o = ct * 16 + ln;
      float bias = bq[o];
      f32x4 acc = {bias, bias, bias, bias};
#pragma unroll
      for (int kc = 0; kc < 8; ++kc) {
        s16x8 bw = *(const s16x8*)(Wqb + o * 256 + kc * 32 + g * 8);
        acc = __builtin_amdgcn_mfma_f32_16x16x32_bf16(a[kc], bw, acc, 0, 0, 0);
      }
#pragma unroll
      for (int j = 0; j < 4; ++j)
        Qo[((size_t)b * HW + (n0 + w * 16 + 4 * g + j)) * 64 + o] = f2bf(acc[j]);
    }
  }
  // ---- K = mfma(forenT, WkT) ----
  {
    int r = w * 16 + ln;
    s16x8 a[8];
#pragma unroll
    for (int kc = 0; kc < 8; ++kc)
      a[kc] = *(const s16x8*)(lds + 16384 + r * 256 + ((kc * 32 + g * 8) ^ ((r & 31) * 8)));
#pragma unroll
    for (int ct = 0; ct < 4; ++ct) {
      int o = ct * 16 + ln;
      float bias = bk[o];
      f32x4 acc = {bias, bias, bias, bias};
#pragma unroll
      for (int kc = 0; kc < 8; ++kc) {
        s16x8 bw = *(const s16x8*)(Wkb + o * 256 + kc * 32 + g * 8);
        acc = __builtin_amdgcn_mfma_f32_16x16x32_bf16(a[kc], bw, acc, 0, 0, 0);
      }
#pragma unroll
      for (int j = 0; j < 4; ++j)
        Ko[((size_t)b * HW + (n0 + w * 16 + 4 * g + j)) * 64 + o] = f2bf(acc[j]);
    }
  }
  // ---- V = mfma(Wv, forenT): D rows = channel ----
#pragma unroll
  for (int rt = 0; rt < 4; ++rt) {
    int o0 = w * 64 + rt * 16;
    s16x8 aw[8];
#pragma unroll
    for (int kc = 0; kc < 8; ++kc)
      aw[kc] = *(const s16x8*)(Wvb + (o0 + ln) * 256 + kc * 32 + g * 8);
#pragma unroll
    for (int ct = 0; ct < 4; ++ct) {
      f32x4 acc;
#pragma unroll
      for (int j = 0; j < 4; ++j) acc[j] = bv[o0 + 4 * g + j];
#pragma unroll
      for (int kc = 0; kc < 8; ++kc) {
        int r = ct * 16 + ln;
        s16x8 bx = *(const s16x8*)(lds + 16384 + r * 256 + ((kc * 32 + g * 8) ^ ((r & 31) * 8)));
        acc = __builtin_amdgcn_mfma_f32_16x16x32_bf16(aw[kc], bx, acc, 0, 0, 0);
      }
#pragma unroll
      for (int j = 0; j < 4; ++j)
        Vo[((size_t)b * DIM + (o0 + 4 * g + j)) * HW + n0 + ct * 16 + ln] = f2bf(acc[j]);
    }
  }
}

// ---------------- kernel 3: fused flash attention + residual ----------------
__global__ __launch_bounds__(256) void attn_fused(
    const u16* __restrict__ Qg, const u16* __restrict__ Kg, const u16* __restrict__ Vg,
    const float* __restrict__ sem, const float* __restrict__ gamma_p,
    float* __restrict__ out) {
  __shared__ u16 lds[24576];  // Ks [0:4096), Vs [4096:20480), P [20480 + w*1024]
  const int t  = threadIdx.x;
  const int b  = blockIdx.x & 7;       // batch -> XCD (L2 pinning of K/V)
  const int n0 = (blockIdx.x >> 3) * 64;
  const int w = t >> 6, lane = t & 63, ln = lane & 15, g = lane >> 4;

  const u16* Qb = Qg + (size_t)b * HW * 64;
  const u16* Kb = Kg + (size_t)b * HW * 64;
  const u16* Vb = Vg + (size_t)b * DIM * HW;

  // Q fragments for this wave's 16 rows (kept in registers all loop)
  s16x8 qf[2];
#pragma unroll
  for (int dc = 0; dc < 2; ++dc)
    qf[dc] = *(const s16x8*)(Qb + ((size_t)(n0 + w * 16 + ln)) * 64 + dc * 32 + g * 8);

  f32x4 O[16];
#pragma unroll
  for (int i = 0; i < 16; ++i) O[i] = (f32x4){0.f, 0.f, 0.f, 0.f};
  float mr[4], lr[4];
#pragma unroll
  for (int j = 0; j < 4; ++j) { mr[j] = -1e30f; lr[j] = 0.f; }

  const int pw = 20480 + w * 1024;

  for (int kt = 0; kt < 64; ++kt) {
    __syncthreads();   // previous tile fully consumed
    // stage K tile 64x64 bf16 (8KB): linear LDS, pre-swizzled global source
#pragma unroll
    for (int i = 0; i < 2; ++i) {
      int tp = (w * 2 + i) * 64 + lane;
      int m = tp >> 3, sl = tp & 7;
      const u16* src = Kb + ((size_t)(kt * 64 + m)) * 64 + ((sl ^ (m & 7)) * 8);
      gload_lds16(src, (void*)(lds + (w * 2 + i) * 512));
    }
    // stage V tile 256x64 bf16 (32KB)
#pragma unroll
    for (int i = 0; i < 8; ++i) {
      int tp = (w * 8 + i) * 64 + lane;
      int c = tp >> 3, sl = tp & 7;
      const u16* src = Vb + (size_t)c * HW + kt * 64 + ((sl ^ (c & 7)) * 8);
      gload_lds16(src, (void*)(lds + 4096 + (w * 8 + i) * 512));
    }
    asm volatile("s_waitcnt vmcnt(0)" ::: "memory");
    __syncthreads();

    // ---- S = Q K^T * 1/8 ----
    f32x4 s[4];
#pragma unroll
    for (int mt = 0; mt < 4; ++mt) s[mt] = (f32x4){0.f, 0.f, 0.f, 0.f};
#pragma unroll
    for (int mt = 0; mt < 4; ++mt) {
      int m = mt * 16 + ln;
#pragma unroll
      for (int dc = 0; dc < 2; ++dc) {
        s16x8 bk_ = *(const s16x8*)(lds + m * 64 + ((dc * 32 + g * 8) ^ ((m & 7) * 8)));
        s[mt] = __builtin_amdgcn_mfma_f32_16x16x32_bf16(qf[dc], bk_, s[mt], 0, 0, 0);
      }
    }
    // ---- online softmax ----
    float mnew[4], corr[4];
#pragma unroll
    for (int j = 0; j < 4; ++j) {
      float mx = -1e30f;
#pragma unroll
      for (int mt = 0; mt < 4; ++mt) { s[mt][j] *= 0.125f; mx = fmaxf(mx, s[mt][j]); }
      mx = fmaxf(mx, __shfl_xor(mx, 1));
      mx = fmaxf(mx, __shfl_xor(mx, 2));
      mx = fmaxf(mx, __shfl_xor(mx, 4));
      mx = fmaxf(mx, __shfl_xor(mx, 8));
      mnew[j] = fmaxf(mr[j], mx);
      corr[j] = __expf(mr[j] - mnew[j]);
      mr[j] = mnew[j];
    }
#pragma unroll
    for (int j = 0; j < 4; ++j) {
      float rs = 0.f;
#pragma unroll
      for (int mt = 0; mt < 4; ++mt) {
        float p = __expf(s[mt][j] - mnew[j]);
        rs += p;
        int r = 4 * g + j, m = mt * 16 + ln;
        lds[pw + r * 64 + (m ^ ((r & 7) * 8))] = f2bf(p);  // per-wave P tile
      }
      rs += __shfl_xor(rs, 1);
      rs += __shfl_xor(rs, 2);
      rs += __shfl_xor(rs, 4);
      rs += __shfl_xor(rs, 8);
      lr[j] = lr[j] * corr[j] + rs;
    }
    // rescale accumulator
#pragma unroll
    for (int ct = 0; ct < 16; ++ct)
#pragma unroll
      for (int j = 0; j < 4; ++j) O[ct][j] *= corr[j];
    // ---- O += P V ----
#pragma unroll
    for (int kc = 0; kc < 2; ++kc) {
      s16x8 ap = *(const s16x8*)(lds + pw + ln * 64 + ((kc * 32 + g * 8) ^ ((ln & 7) * 8)));
#pragma unroll
      for (int ct = 0; ct < 16; ++ct) {
        int c = ct * 16 + ln;
        s16x8 bv_ = *(const s16x8*)(lds + 4096 + c * 64 + ((kc * 32 + g * 8) ^ ((c & 7) * 8)));
        O[ct] = __builtin_amdgcn_mfma_f32_16x16x32_bf16(ap, bv_, O[ct], 0, 0, 0);
      }
    }
  }
  // ---- epilogue: out = sem + gamma * (O / l) ----
  float gm = gamma_p[0];
  float invl[4];
#pragma unroll
  for (int j = 0; j < 4; ++j) invl[j] = 1.f / lr[j];
#pragma unroll
  for (int ct = 0; ct < 16; ++ct) {
#pragma unroll
    for (int j = 0; j < 4; ++j) {
      int c = ct * 16 + ln;
      int n = n0 + w * 16 + 4 * g + j;
      size_t idx = ((size_t)b * DIM + c) * HW + n;
      out[idx] = sem[idx] + gm * (O[ct][j] * invl[j]);
    }
  }
}

extern "C" void kernel_launch(void* const* d_in, const int* in_sizes, int n_in,
                              void* d_out, int out_size, void* d_ws, size_t ws_size,
                              hipStream_t stream) {
  const float* sem   = (const float*)d_in[0];
  const float* foren = (const float*)d_in[1];
  const float* Wq    = (const float*)d_in[2];
  const float* bq    = (const float*)d_in[3];
  const float* Wk    = (const float*)d_in[4];
  const float* bk    = (const float*)d_in[5];
  const float* Wv    = (const float*)d_in[6];
  const float* bv    = (const float*)d_in[7];
  const float* gamma = (const float*)d_in[8];
  float* out = (float*)d_out;

  // workspace layout (bf16 elements): Wq 16K | Wk 16K | Wv 64K | Q 2M | K 2M | V 8M  (~24.2 MB)
  u16* Wqb = (u16*)d_ws;
  u16* Wkb = Wqb + 16384;
  u16* Wvb = Wkb + 16384;
  u16* Q   = Wvb + 65536;
  u16* K   = Q + (size_t)NB * HW * 64;
  u16* V   = K + (size_t)NB * HW * 64;

  prep_w  <<<384, 256, 0, stream>>>(Wq, Wk, Wv, Wqb);
  proj_qkv<<<512, 256, 0, stream>>>(sem, foren, Wqb, Wkb, Wvb, bq, bk, bv, Q, K, V);
  attn_fused<<<512, 256, 0, stream>>>(Q, K, V, sem, gamma, out);
}

// Round 2
// 168.894 us; speedup vs baseline: 2.1164x; 2.1164x over previous
//
#include <hip/hip_runtime.h>
#include <hip/hip_bf16.h>
#include <stdint.h>

typedef unsigned short u16;
typedef unsigned int u32;
typedef short s16x8 __attribute__((ext_vector_type(8)));
typedef float f32x4 __attribute__((ext_vector_type(4)));

#define DIM 256
#define HW  4096
#define NB  8
#define QSCL 0.18033688011112042f   // 0.125 * log2(e): fold softmax scale + log2-domain into Q

__device__ __forceinline__ u16 f2bf(float f) {
  union { float f; unsigned u; } v; v.f = f;
  unsigned r = v.u + 0x7FFFu + ((v.u >> 16) & 1u);
  return (u16)(r >> 16);
}

__device__ __forceinline__ float fexp2(float x) { return __builtin_amdgcn_exp2f(x); }

typedef __attribute__((address_space(1))) const void gvoid_c;
typedef __attribute__((address_space(3))) void lvoid;
__device__ __forceinline__ void gload_lds16(const void* g, void* l) {
  __builtin_amdgcn_global_load_lds((gvoid_c*)g, (lvoid*)l, 16, 0, 0);
}

// ---------------- kernel 1: weights f32 -> bf16 (+ Q scale fold, knmax init) ----------------
__global__ void prep_w(const float* __restrict__ Wq, const float* __restrict__ Wk,
                       const float* __restrict__ Wv, u16* __restrict__ dst,
                       u32* __restrict__ knmax_u) {
  int idx = blockIdx.x * 256 + threadIdx.x;   // 0 .. 98303
  if (blockIdx.x == 0 && threadIdx.x < 8) knmax_u[threadIdx.x] = 0u;
  float v;
  if (idx < 16384)        v = Wq[idx] * QSCL;
  else if (idx < 32768)   v = Wk[idx - 16384];
  else                    v = Wv[idx - 32768];
  dst[idx] = f2bf(v);
}

// ---------------- kernel 2: QKV projections (MFMA) + q-row norms + key-norm max ----------------
// Q,K stored [B][N][64] (d contiguous); V stored [B][256][N] (n contiguous)
__global__ __launch_bounds__(256) void proj_qkv(
    const float* __restrict__ sem, const float* __restrict__ foren,
    const u16* __restrict__ Wqb, const u16* __restrict__ Wkb, const u16* __restrict__ Wvb,
    const float* __restrict__ bq, const float* __restrict__ bk, const float* __restrict__ bv,
    u16* __restrict__ Qo, u16* __restrict__ Ko, u16* __restrict__ Vo,
    float* __restrict__ qnsq, u32* __restrict__ knmax_u) {
  __shared__ u16 lds[32768];  // [0:16384) sem^T [px][256], [16384:32768) foren^T
  const int t  = threadIdx.x;
  const int b  = blockIdx.x & 7;
  const int n0 = (blockIdx.x >> 3) * 64;
  // ---- load + transpose X into LDS (bf16, XOR-swizzled) ----
  {
    const int px  = t & 63;
    const int cb  = (t >> 6) * 8;
    const int swz = (px & 31) * 8;
    for (int i = 0; i < 8; ++i) {
      int c0 = i * 32 + cb;
      size_t gb = ((size_t)b * DIM + c0) * HW + n0 + px;
      s16x8 us, uf;
#pragma unroll
      for (int j = 0; j < 8; ++j) {
        us[j] = (short)f2bf(sem[gb + (size_t)j * HW]);
        uf[j] = (short)f2bf(foren[gb + (size_t)j * HW]);
      }
      int li = px * 256 + (c0 ^ swz);
      *(s16x8*)(lds + li)         = us;
      *(s16x8*)(lds + 16384 + li) = uf;
    }
  }
  __syncthreads();
  const int w = t >> 6, lane = t & 63, ln = lane & 15, g = lane >> 4;

  // ---- Q = mfma(semT, WqT): D rows = px ----  (Wq pre-scaled by QSCL)
  {
    int r = w * 16 + ln;
    s16x8 a[8];
#pragma unroll
    for (int kc = 0; kc < 8; ++kc)
      a[kc] = *(const s16x8*)(lds + r * 256 + ((kc * 32 + g * 8) ^ ((r & 31) * 8)));
    float sq[4] = {0.f, 0.f, 0.f, 0.f};
#pragma unroll
    for (int ct = 0; ct < 4; ++ct) {
      int o = ct * 16 + ln;
      float bias = bq[o] * QSCL;
      f32x4 acc = {bias, bias, bias, bias};
#pragma unroll
      for (int kc = 0; kc < 8; ++kc) {
        s16x8 bw = *(const s16x8*)(Wqb + o * 256 + kc * 32 + g * 8);
        acc = __builtin_amdgcn_mfma_f32_16x16x32_bf16(a[kc], bw, acc, 0, 0, 0);
      }
#pragma unroll
      for (int j = 0; j < 4; ++j) {
        Qo[((size_t)b * HW + (n0 + w * 16 + 4 * g + j)) * 64 + o] = f2bf(acc[j]);
        sq[j] += acc[j] * acc[j];
      }
    }
#pragma unroll
    for (int j = 0; j < 4; ++j) {
      sq[j] += __shfl_xor(sq[j], 1);
      sq[j] += __shfl_xor(sq[j], 2);
      sq[j] += __shfl_xor(sq[j], 4);
      sq[j] += __shfl_xor(sq[j], 8);
    }
    if (ln == 0)
#pragma unroll
      for (int j = 0; j < 4; ++j)
        qnsq[(size_t)b * HW + n0 + w * 16 + 4 * g + j] = sq[j];
  }
  // ---- K = mfma(forenT, WkT) ----
  {
    int r = w * 16 + ln;
    s16x8 a[8];
#pragma unroll
    for (int kc = 0; kc < 8; ++kc)
      a[kc] = *(const s16x8*)(lds + 16384 + r * 256 + ((kc * 32 + g * 8) ^ ((r & 31) * 8)));
    float sk[4] = {0.f, 0.f, 0.f, 0.f};
#pragma unroll
    for (int ct = 0; ct < 4; ++ct) {
      int o = ct * 16 + ln;
      float bias = bk[o];
      f32x4 acc = {bias, bias, bias, bias};
#pragma unroll
      for (int kc = 0; kc < 8; ++kc) {
        s16x8 bw = *(const s16x8*)(Wkb + o * 256 + kc * 32 + g * 8);
        acc = __builtin_amdgcn_mfma_f32_16x16x32_bf16(a[kc], bw, acc, 0, 0, 0);
      }
#pragma unroll
      for (int j = 0; j < 4; ++j) {
        Ko[((size_t)b * HW + (n0 + w * 16 + 4 * g + j)) * 64 + o] = f2bf(acc[j]);
        sk[j] += acc[j] * acc[j];
      }
    }
#pragma unroll
    for (int j = 0; j < 4; ++j) {
      sk[j] += __shfl_xor(sk[j], 1);
      sk[j] += __shfl_xor(sk[j], 2);
      sk[j] += __shfl_xor(sk[j], 4);
      sk[j] += __shfl_xor(sk[j], 8);
    }
    float km = fmaxf(fmaxf(sk[0], sk[1]), fmaxf(sk[2], sk[3]));
    km = fmaxf(km, __shfl_xor(km, 16));
    km = fmaxf(km, __shfl_xor(km, 32));
    if (lane == 0) atomicMax(knmax_u + b, __float_as_uint(km));
  }
  // ---- V = mfma(Wv, forenT): D rows = channel ----
#pragma unroll
  for (int rt = 0; rt < 4; ++rt) {
    int o0 = w * 64 + rt * 16;
    s16x8 aw[8];
#pragma unroll
    for (int kc = 0; kc < 8; ++kc)
      aw[kc] = *(const s16x8*)(Wvb + (o0 + ln) * 256 + kc * 32 + g * 8);
#pragma unroll
    for (int ct = 0; ct < 4; ++ct) {
      f32x4 acc;
#pragma unroll
      for (int j = 0; j < 4; ++j) acc[j] = bv[o0 + 4 * g + j];
#pragma unroll
      for (int kc = 0; kc < 8; ++kc) {
        int r = ct * 16 + ln;
        s16x8 bx = *(const s16x8*)(lds + 16384 + r * 256 + ((kc * 32 + g * 8) ^ ((r & 31) * 8)));
        acc = __builtin_amdgcn_mfma_f32_16x16x32_bf16(aw[kc], bx, acc, 0, 0, 0);
      }
#pragma unroll
      for (int j = 0; j < 4; ++j)
        Vo[((size_t)b * DIM + (o0 + 4 * g + j)) * HW + n0 + ct * 16 + ln] = f2bf(acc[j]);
    }
  }
}

// ---------------- kernel 3: fused attention (bound-max softmax) + residual ----------------
// 512 threads = 8 waves. Q-tile 128 rows. QK: wave w -> rows w*16.
// PV: wave (wr=w>>2, wc=w&3) -> rows wr*64, channels wc*64.
__global__ __launch_bounds__(512, 2) void attn2(
    const u16* __restrict__ Qg, const u16* __restrict__ Kg, const u16* __restrict__ Vg,
    const float* __restrict__ qnsq, const u32* __restrict__ knmax_u,
    const float* __restrict__ sem, const float* __restrict__ gamma_p,
    float* __restrict__ out) {
  // u16 units: Ks[2] @ 0 (2x4096), Vs[2] @ 8192 (2x16384), P @ 40960 (8192)  => 96KB
  __shared__ u16 lds[49152];
  const int t  = threadIdx.x;
  const int b  = blockIdx.x & 7;            // batch -> XCD (K/V L2-pinned, 2.5MB/XCD)
  const int n0 = (blockIdx.x >> 3) << 7;    // *128
  const int w = t >> 6, lane = t & 63, ln = lane & 15, g = lane >> 4;
  const int wr = w >> 2, wc = w & 3;

  const u16* Qb = Qg + (size_t)b * HW * 64;
  const u16* Kb = Kg + (size_t)b * HW * 64;
  const u16* Vb = Vg + (size_t)b * DIM * HW;

  // Q fragments: rows n0 + w*16 + ln
  s16x8 qf[2];
#pragma unroll
  for (int dc = 0; dc < 2; ++dc)
    qf[dc] = *(const s16x8*)(Qb + ((size_t)(n0 + w * 16 + ln)) * 64 + dc * 32 + g * 8);

  // safe softmax shift (log2 domain): m^ = sqrt(|q|^2 * max|k|^2) * 1.02 >= max_k(q.k)
  float mrow[4];
  {
    float knsq = __uint_as_float(knmax_u[b]);
#pragma unroll
    for (int j = 0; j < 4; ++j) {
      float qq = qnsq[(size_t)b * HW + n0 + w * 16 + 4 * g + j];
      mrow[j] = sqrtf(qq * knsq) * 1.02f;
    }
  }

  f32x4 O[16];
#pragma unroll
  for (int i = 0; i < 16; ++i) O[i] = (f32x4){0.f, 0.f, 0.f, 0.f};
  f32x4 lacc[4];
#pragma unroll
  for (int i = 0; i < 4; ++i) lacc[i] = (f32x4){0.f, 0.f, 0.f, 0.f};
  s16x8 ones;
#pragma unroll
  for (int e = 0; e < 8; ++e) ones[e] = (short)0x3F80;   // bf16 1.0

  auto STAGE = [&](int buf, int kt) {
    {
      int m = t >> 3, sl = t & 7;
      const u16* src = Kb + ((size_t)(kt * 64 + m)) * 64 + ((sl ^ (m & 7)) * 8);
      gload_lds16(src, (void*)(lds + buf * 4096 + w * 512));
    }
#pragma unroll
    for (int i = 0; i < 4; ++i) {
      int c = i * 64 + (t >> 3), sl = t & 7;
      const u16* src = Vb + (size_t)c * HW + kt * 64 + ((sl ^ (c & 7)) * 8);
      gload_lds16(src, (void*)(lds + 8192 + buf * 16384 + i * 4096 + w * 512));
    }
  };

  STAGE(0, 0);
  asm volatile("s_waitcnt vmcnt(0)" ::: "memory");
  __syncthreads();

  for (int kt = 0; kt < 64; ++kt) {
    const int cur = kt & 1;
    if (kt < 63) STAGE(cur ^ 1, kt + 1);   // overlap next-tile staging with this tile's compute

    // ---- S = Q'K^T (log2 domain) ----
    const u16* Kc = lds + cur * 4096;
    f32x4 s[4];
#pragma unroll
    for (int mt = 0; mt < 4; ++mt) s[mt] = (f32x4){0.f, 0.f, 0.f, 0.f};
#pragma unroll
    for (int mt = 0; mt < 4; ++mt) {
      int m = mt * 16 + ln;
#pragma unroll
      for (int dc = 0; dc < 2; ++dc) {
        s16x8 kb = *(const s16x8*)(Kc + m * 64 + (((dc * 4 + g) ^ (m & 7)) * 8));
        s[mt] = __builtin_amdgcn_mfma_f32_16x16x32_bf16(qf[dc], kb, s[mt], 0, 0, 0);
      }
    }
    // ---- p = exp2(s - m^), write P tile (swizzled) ----
#pragma unroll
    for (int j = 0; j < 4; ++j) {
      int r = w * 16 + 4 * g + j;
#pragma unroll
      for (int mt = 0; mt < 4; ++mt) {
        float p = fexp2(s[mt][j] - mrow[j]);
        int key = mt * 16 + ln;
        int e = (((key >> 3) ^ (r & 7)) << 3) | (key & 7);
        lds[40960 + r * 64 + e] = f2bf(p);
      }
    }
    __syncthreads();   // P visible to all waves

    // ---- O += P V ;  l += P . 1 (wc==0 only) ----
    const u16* Vc = lds + 8192 + cur * 16384;
#pragma unroll
    for (int kc = 0; kc < 2; ++kc) {
      s16x8 ap[4];
#pragma unroll
      for (int rt = 0; rt < 4; ++rt) {
        int r = wr * 64 + rt * 16 + ln;
        ap[rt] = *(const s16x8*)(lds + 40960 + r * 64 + (((kc * 4 + g) ^ (r & 7)) * 8));
      }
      if (wc == 0) {
#pragma unroll
        for (int rt = 0; rt < 4; ++rt)
          lacc[rt] = __builtin_amdgcn_mfma_f32_16x16x32_bf16(ap[rt], ones, lacc[rt], 0, 0, 0);
      }
#pragma unroll
      for (int ct = 0; ct < 4; ++ct) {
        int c = wc * 64 + ct * 16 + ln;
        s16x8 bv_ = *(const s16x8*)(Vc + c * 64 + (((kc * 4 + g) ^ (c & 7)) * 8));
#pragma unroll
        for (int rt = 0; rt < 4; ++rt)
          O[rt * 4 + ct] = __builtin_amdgcn_mfma_f32_16x16x32_bf16(ap[rt], bv_, O[rt * 4 + ct], 0, 0, 0);
      }
    }
    asm volatile("s_waitcnt vmcnt(0)" ::: "memory");  // next tile staged
    __syncthreads();   // everyone done with cur + P
  }

  // ---- broadcast l, epilogue ----
  float* lL = (float*)(lds + 40960);
  if (wc == 0 && ln == 0) {
#pragma unroll
    for (int rt = 0; rt < 4; ++rt)
#pragma unroll
      for (int j = 0; j < 4; ++j)
        lL[wr * 64 + rt * 16 + 4 * g + j] = lacc[rt][j];
  }
  __syncthreads();
  float gm = gamma_p[0];
  float inv[16];
#pragma unroll
  for (int rt = 0; rt < 4; ++rt)
#pragma unroll
    for (int j = 0; j < 4; ++j)
      inv[rt * 4 + j] = 1.f / lL[wr * 64 + rt * 16 + 4 * g + j];
#pragma unroll
  for (int rt = 0; rt < 4; ++rt) {
#pragma unroll
    for (int ct = 0; ct < 4; ++ct) {
      int c = wc * 64 + ct * 16 + ln;
      int nb_ = n0 + wr * 64 + rt * 16 + 4 * g;
      size_t base = ((size_t)(b * DIM + c)) * HW + nb_;
      f32x4 sv = *(const f32x4*)(sem + base);
      f32x4 o;
#pragma unroll
      for (int j = 0; j < 4; ++j)
        o[j] = sv[j] + gm * (O[rt * 4 + ct][j] * inv[rt * 4 + j]);
      *(f32x4*)(out + base) = o;
    }
  }
}

extern "C" void kernel_launch(void* const* d_in, const int* in_sizes, int n_in,
                              void* d_out, int out_size, void* d_ws, size_t ws_size,
                              hipStream_t stream) {
  const float* sem   = (const float*)d_in[0];
  const float* foren = (const float*)d_in[1];
  const float* Wq    = (const float*)d_in[2];
  const float* bq    = (const float*)d_in[3];
  const float* Wk    = (const float*)d_in[4];
  const float* bk    = (const float*)d_in[5];
  const float* Wv    = (const float*)d_in[6];
  const float* bv    = (const float*)d_in[7];
  const float* gamma = (const float*)d_in[8];
  float* out = (float*)d_out;

  // ws (u16 units): Wq 16K | Wk 16K | Wv 64K | Q 2M | K 2M | V 8M | qnsq f32 32K | knmax u32 8
  u16* Wqb = (u16*)d_ws;
  u16* Wkb = Wqb + 16384;
  u16* Wvb = Wkb + 16384;
  u16* Q   = Wvb + 65536;
  u16* K   = Q + (size_t)NB * HW * 64;
  u16* V   = K + (size_t)NB * HW * 64;
  float* qnsq = (float*)(V + (size_t)NB * DIM * HW);
  u32* knmax_u = (u32*)(qnsq + (size_t)NB * HW);

  prep_w  <<<384, 256, 0, stream>>>(Wq, Wk, Wv, Wqb, knmax_u);
  proj_qkv<<<512, 256, 0, stream>>>(sem, foren, Wqb, Wkb, Wvb, bq, bk, bv, Q, K, V, qnsq, knmax_u);
  attn2   <<<256, 512, 0, stream>>>(Q, K, V, qnsq, knmax_u, sem, gamma, out);
}

// Round 3
// 166.155 us; speedup vs baseline: 2.1513x; 1.0165x over previous
//
#include <hip/hip_runtime.h>
#include <stdint.h>

typedef unsigned short u16;
typedef unsigned int u32;
typedef short s16x8 __attribute__((ext_vector_type(8)));
typedef float f32x4 __attribute__((ext_vector_type(4)));
typedef float f32x16 __attribute__((ext_vector_type(16)));
typedef u32 u32x2 __attribute__((ext_vector_type(2)));

#define DIM 256
#define HW  4096
#define NB  8
#define QSCL 0.18033688011112042f   // 0.125 * log2(e): softmax scale + log2-domain folded into Q

template <int N> struct ic { static constexpr int value = N; };

__device__ __forceinline__ u16 f2bf(float f) {
  union { float f; unsigned u; } v; v.f = f;
  unsigned r = v.u + 0x7FFFu + ((v.u >> 16) & 1u);
  return (u16)(r >> 16);
}
__device__ __forceinline__ float fexp2(float x) { return __builtin_amdgcn_exp2f(x); }

typedef __attribute__((address_space(1))) const void gvoid_c;
typedef __attribute__((address_space(3))) void lvoid;
__device__ __forceinline__ void gload_lds16(const void* g, void* l) {
  __builtin_amdgcn_global_load_lds((gvoid_c*)g, (lvoid*)l, 16, 0, 0);
}
__device__ __forceinline__ f32x16 mfma32(s16x8 a, s16x8 b, f32x16 c) {
  return __builtin_amdgcn_mfma_f32_32x32x16_bf16(a, b, c, 0, 0, 0);
}
__device__ __forceinline__ f32x4 mfma16(s16x8 a, s16x8 b, f32x4 c) {
  return __builtin_amdgcn_mfma_f32_16x16x32_bf16(a, b, c, 0, 0, 0);
}

// ---------------- kernel 1: weights f32 -> bf16 (+ Q scale fold, knmax init) ----------------
__global__ void prep_w(const float* __restrict__ Wq, const float* __restrict__ Wk,
                       const float* __restrict__ Wv, u16* __restrict__ dst,
                       u32* __restrict__ knmax_u) {
  int idx = blockIdx.x * 256 + threadIdx.x;   // 0 .. 98303
  if (blockIdx.x == 0 && threadIdx.x < 8) knmax_u[threadIdx.x] = 0u;
  float v;
  if (idx < 16384)        v = Wq[idx] * QSCL;
  else if (idx < 32768)   v = Wk[idx - 16384];
  else                    v = Wv[idx - 32768];
  dst[idx] = f2bf(v);
}

// ---------------- kernel 2a: Q projection + q-row scaled norms ----------------
// Q stored [B][N][64] (d contiguous)
__global__ __launch_bounds__(256) void proj_q(
    const float* __restrict__ sem, const u16* __restrict__ Wqb, const float* __restrict__ bq,
    u16* __restrict__ Qo, float* __restrict__ qnsq) {
  __shared__ u16 lds[16384];  // semT [64 px][256 c], swizzled
  const int t = threadIdx.x, b = blockIdx.x & 7, n0 = (blockIdx.x >> 3) * 64;
  {
    const int px = t & 63, cb = (t >> 6) * 8, swz = (px & 31) * 8;
    for (int i = 0; i < 8; ++i) {
      int c0 = i * 32 + cb;
      size_t gb = ((size_t)b * DIM + c0) * HW + n0 + px;
      s16x8 us;
#pragma unroll
      for (int j = 0; j < 8; ++j) us[j] = (short)f2bf(sem[gb + (size_t)j * HW]);
      *(s16x8*)(lds + px * 256 + (c0 ^ swz)) = us;
    }
  }
  __syncthreads();
  const int w = t >> 6, lane = t & 63, l15 = lane & 15, g = lane >> 4;
  const int px = w * 16 + l15;
  s16x8 bx[8];
#pragma unroll
  for (int kc = 0; kc < 8; ++kc)
    bx[kc] = *(const s16x8*)(lds + px * 256 + (((kc * 4 + g) ^ (px & 31)) * 8));
  float nrm = 0.f;
#pragma unroll
  for (int ct = 0; ct < 4; ++ct) {
    f32x4 bb = *(const f32x4*)(bq + ct * 16 + 4 * g);
    f32x4 acc;
#pragma unroll
    for (int j = 0; j < 4; ++j) acc[j] = bb[j] * QSCL;
#pragma unroll
    for (int kc = 0; kc < 8; ++kc) {
      s16x8 aw = *(const s16x8*)(Wqb + (ct * 16 + l15) * 256 + kc * 32 + g * 8);
      acc = mfma16(aw, bx[kc], acc);
    }
    u32 lo = (u32)f2bf(acc[0]) | ((u32)f2bf(acc[1]) << 16);
    u32 hi = (u32)f2bf(acc[2]) | ((u32)f2bf(acc[3]) << 16);
    u32x2 pk; pk[0] = lo; pk[1] = hi;
    *(u32x2*)(Qo + ((size_t)b * HW + n0 + px) * 64 + ct * 16 + 4 * g) = pk;
#pragma unroll
    for (int j = 0; j < 4; ++j) nrm += acc[j] * acc[j];
  }
  nrm += __shfl_xor(nrm, 16);
  nrm += __shfl_xor(nrm, 32);
  if (g == 0) qnsq[(size_t)b * HW + n0 + px] = nrm;
}

// ---------------- kernel 2b: K,V projections + key-norm max ----------------
// K stored [B][N][64]; V stored [B][256][N]
__global__ __launch_bounds__(256) void proj_kv(
    const float* __restrict__ foren, const u16* __restrict__ Wkb, const u16* __restrict__ Wvb,
    const float* __restrict__ bk, const float* __restrict__ bv,
    u16* __restrict__ Ko, u16* __restrict__ Vo, u32* __restrict__ knmax_u) {
  __shared__ u16 lds[16384];  // forenT
  const int t = threadIdx.x, b = blockIdx.x & 7, n0 = (blockIdx.x >> 3) * 64;
  {
    const int px = t & 63, cb = (t >> 6) * 8, swz = (px & 31) * 8;
    for (int i = 0; i < 8; ++i) {
      int c0 = i * 32 + cb;
      size_t gb = ((size_t)b * DIM + c0) * HW + n0 + px;
      s16x8 uf;
#pragma unroll
      for (int j = 0; j < 8; ++j) uf[j] = (short)f2bf(foren[gb + (size_t)j * HW]);
      *(s16x8*)(lds + px * 256 + (c0 ^ swz)) = uf;
    }
  }
  __syncthreads();
  const int w = t >> 6, lane = t & 63, l15 = lane & 15, g = lane >> 4;
  // ---- K: wave w handles px-group w*16 ----
  {
    const int px = w * 16 + l15;
    s16x8 bx[8];
#pragma unroll
    for (int kc = 0; kc < 8; ++kc)
      bx[kc] = *(const s16x8*)(lds + px * 256 + (((kc * 4 + g) ^ (px & 31)) * 8));
    float nrm = 0.f;
#pragma unroll
    for (int ct = 0; ct < 4; ++ct) {
      f32x4 acc = *(const f32x4*)(bk + ct * 16 + 4 * g);
#pragma unroll
      for (int kc = 0; kc < 8; ++kc) {
        s16x8 aw = *(const s16x8*)(Wkb + (ct * 16 + l15) * 256 + kc * 32 + g * 8);
        acc = mfma16(aw, bx[kc], acc);
      }
      u32 lo = (u32)f2bf(acc[0]) | ((u32)f2bf(acc[1]) << 16);
      u32 hi = (u32)f2bf(acc[2]) | ((u32)f2bf(acc[3]) << 16);
      u32x2 pk; pk[0] = lo; pk[1] = hi;
      *(u32x2*)(Ko + ((size_t)b * HW + n0 + px) * 64 + ct * 16 + 4 * g) = pk;
#pragma unroll
      for (int j = 0; j < 4; ++j) nrm += acc[j] * acc[j];
    }
    nrm += __shfl_xor(nrm, 16);
    nrm += __shfl_xor(nrm, 32);
    nrm = fmaxf(nrm, __shfl_xor(nrm, 1));
    nrm = fmaxf(nrm, __shfl_xor(nrm, 2));
    nrm = fmaxf(nrm, __shfl_xor(nrm, 4));
    nrm = fmaxf(nrm, __shfl_xor(nrm, 8));
    if (lane == 0) atomicMax(knmax_u + b, __float_as_uint(nrm));
  }
  // ---- V: wave w handles c-group w*64 (cuts Wv L2 re-reads 4x) ----
#pragma unroll
  for (int ct2 = 0; ct2 < 4; ++ct2) {
    const int c0 = w * 64 + ct2 * 16;
    s16x8 aw[8];
#pragma unroll
    for (int kc = 0; kc < 8; ++kc)
      aw[kc] = *(const s16x8*)(Wvb + (c0 + l15) * 256 + kc * 32 + g * 8);
#pragma unroll
    for (int pxt = 0; pxt < 4; ++pxt) {
      const int px = pxt * 16 + l15;
      f32x4 acc = *(const f32x4*)(bv + c0 + 4 * g);
#pragma unroll
      for (int kc = 0; kc < 8; ++kc) {
        s16x8 bxp = *(const s16x8*)(lds + px * 256 + (((kc * 4 + g) ^ (px & 31)) * 8));
        acc = mfma16(aw[kc], bxp, acc);
      }
#pragma unroll
      for (int j = 0; j < 4; ++j)
        Vo[((size_t)b * DIM + c0 + 4 * g + j) * HW + n0 + pxt * 16 + l15] = f2bf(acc[j]);
    }
  }
}

// ---------------- kernel 3: fused attention (bound-max softmax, swapped QK, 32x32) ----------------
// 512 threads = 8 waves, Q-tile 128 rows, KV-tile 64.
// QK roles: wave (rr=w&3, hh=w>>2): S^T for keys hh*32+[0,32) x qrows rr*32+[0,32).
// PV roles: wave (rw=w>>2, cw=w&3): O for rows rw*64+[0,64) x channels cw*64+[0,64).
__global__ __launch_bounds__(512, 1) void attn3(
    const u16* __restrict__ Qg, const u16* __restrict__ Kg, const u16* __restrict__ Vg,
    const float* __restrict__ qnsq, const u32* __restrict__ knmax_u,
    const float* __restrict__ sem, const float* __restrict__ gamma_p,
    float* __restrict__ out) {
  // bytes: K0@0 K1@8192 | V0@16384 V1@49152 | P@81920 (16KB) | lsum@98304 (1KB)
  __shared__ u16 lds[49664];
  char* ldsb = (char*)lds;
  const int t = threadIdx.x;
  const int b = blockIdx.x & 7;            // batch -> XCD (K/V/Q ~3MB L2-pinned)
  const int n0 = (blockIdx.x >> 3) << 7;   // *128
  const int w = t >> 6, lane = t & 63;
  const int l31 = lane & 31, g5 = lane >> 5;

  const u16* Qb = Qg + (size_t)b * HW * 64;
  const u16* Kb = Kg + (size_t)b * HW * 64;
  const u16* Vb = Vg + (size_t)b * DIM * HW;

  // QK roles
  const int hh = w >> 2, rr = w & 3;
  const int key0 = hh * 32 + l31;
  const int qrow = rr * 32 + l31;
  int ka[4];
#pragma unroll
  for (int ks = 0; ks < 4; ++ks)
    ka[ks] = key0 * 128 + (((ks * 2 + g5) ^ (key0 & 7)) * 16);
  s16x8 qb[4];
#pragma unroll
  for (int ks = 0; ks < 4; ++ks)
    qb[ks] = *(const s16x8*)(Qb + (size_t)(n0 + qrow) * 64 + ks * 16 + g5 * 8);
  int pw_[4];
#pragma unroll
  for (int jg = 0; jg < 4; ++jg)
    pw_[jg] = 81920 + qrow * 128 + (((hh * 4 + jg) ^ (qrow & 7)) * 16) + g5 * 8;
  const float mr = sqrtf(qnsq[(size_t)b * HW + n0 + qrow] * __uint_as_float(knmax_u[b])) * 1.02f;

  // PV roles
  const int rw = w >> 2, cw = w & 3;
  int pa[2][4], va[2][4];
#pragma unroll
  for (int rt = 0; rt < 2; ++rt)
#pragma unroll
    for (int ks = 0; ks < 4; ++ks) {
      int r = rw * 64 + rt * 32 + l31;
      pa[rt][ks] = 81920 + r * 128 + (((ks * 2 + g5) ^ (r & 7)) * 16);
    }
#pragma unroll
  for (int ct = 0; ct < 2; ++ct)
#pragma unroll
    for (int ks = 0; ks < 4; ++ks) {
      int c = cw * 64 + ct * 32 + l31;
      va[ct][ks] = 16384 + c * 128 + (((ks * 2 + g5) ^ (c & 7)) * 16);
    }

  f32x16 O[4] = {};
  float lreg = 0.f;

  // staging: linear LDS dest, inverse-swizzled global source (same XOR involution as reads)
  const int srow = lane >> 3;
  const int sx = ((lane & 7) ^ srow) * 8;

  auto STAGE = [&](int buf, int kt) {
    const u16* ksrc = Kb + ((size_t)(kt * 64 + w * 8 + srow)) * 64 + sx;
    gload_lds16(ksrc, (void*)(lds + buf * 4096 + w * 512));
#pragma unroll
    for (int i = 0; i < 4; ++i) {
      int c = (i * 8 + w) * 8 + srow;
      const u16* vsrc = Vb + (size_t)c * HW + kt * 64 + sx;
      gload_lds16(vsrc, (void*)(lds + 8192 + buf * 16384 + (i * 8 + w) * 512));
    }
  };

  auto tile = [&](auto BUFC, int kt, bool dostage) {
    constexpr int BUF = decltype(BUFC)::value;
    if (dostage) STAGE(BUF ^ 1, kt + 1);
    // ---- S^T = K Q (log2 domain, scale pre-folded) ----
    f32x16 sc = {};
#pragma unroll
    for (int ks = 0; ks < 4; ++ks) {
      s16x8 ak = *(const s16x8*)(ldsb + ka[ks] + BUF * 8192);
      sc = mfma32(ak, qb[ks], sc);
    }
    // ---- p = exp2(s - m^): lane-local row, packed b64 P writes ----
#pragma unroll
    for (int jg = 0; jg < 4; ++jg) {
      float p0 = fexp2(sc[jg * 4 + 0] - mr);
      float p1 = fexp2(sc[jg * 4 + 1] - mr);
      float p2 = fexp2(sc[jg * 4 + 2] - mr);
      float p3 = fexp2(sc[jg * 4 + 3] - mr);
      lreg += (p0 + p1) + (p2 + p3);
      u32 w0, w1;
      asm("v_cvt_pk_bf16_f32 %0, %1, %2" : "=v"(w0) : "v"(p0), "v"(p1));
      asm("v_cvt_pk_bf16_f32 %0, %1, %2" : "=v"(w1) : "v"(p2), "v"(p3));
      u32x2 pk; pk[0] = w0; pk[1] = w1;
      *(u32x2*)(ldsb + pw_[jg]) = pk;
    }
    // barrier 1: P visible; do NOT drain vmcnt (staging stays in flight)
    asm volatile("s_waitcnt lgkmcnt(0)" ::: "memory");
    __builtin_amdgcn_s_barrier();
    __builtin_amdgcn_sched_barrier(0);
    // ---- O += P V ----
#pragma unroll
    for (int ks = 0; ks < 4; ++ks) {
      s16x8 ap0 = *(const s16x8*)(ldsb + pa[0][ks]);
      s16x8 ap1 = *(const s16x8*)(ldsb + pa[1][ks]);
      s16x8 vb0 = *(const s16x8*)(ldsb + va[0][ks] + BUF * 32768);
      s16x8 vb1 = *(const s16x8*)(ldsb + va[1][ks] + BUF * 32768);
      O[0] = mfma32(ap0, vb0, O[0]);
      O[1] = mfma32(ap0, vb1, O[1]);
      O[2] = mfma32(ap1, vb0, O[2]);
      O[3] = mfma32(ap1, vb1, O[3]);
    }
    // barrier 2: staging done (vmcnt(0)) + all P/V reads complete
    __syncthreads();
  };

  STAGE(0, 0);
  __syncthreads();
  for (int kt = 0; kt < 64; kt += 2) {
    tile(ic<0>{}, kt, true);
    tile(ic<1>{}, kt + 1, kt + 2 < 64);
  }

  // ---- merge l across (g5, h) then epilogue ----
  float* lfp = (float*)(ldsb + 98304);
  float ls = lreg + __shfl_xor(lreg, 32);
  if (lane < 32) lfp[hh * 128 + qrow] = ls;
  __syncthreads();
  const float gm = gamma_p[0];
#pragma unroll
  for (int rt = 0; rt < 2; ++rt) {
#pragma unroll
    for (int jg = 0; jg < 4; ++jg) {
      const int noff = rw * 64 + rt * 32 + jg * 8 + 4 * g5;
      f32x4 l0 = *(const f32x4*)(lfp + noff);
      f32x4 l1 = *(const f32x4*)(lfp + 128 + noff);
      f32x4 inv;
#pragma unroll
      for (int j = 0; j < 4; ++j) inv[j] = __builtin_amdgcn_rcpf(l0[j] + l1[j]);
#pragma unroll
      for (int ct = 0; ct < 2; ++ct) {
        const int c = cw * 64 + ct * 32 + l31;
        size_t base = ((size_t)b * DIM + c) * HW + n0 + noff;
        f32x4 sv = *(const f32x4*)(sem + base);
        f32x4 ov;
#pragma unroll
        for (int j = 0; j < 4; ++j)
          ov[j] = sv[j] + gm * (O[rt * 2 + ct][jg * 4 + j] * inv[j]);
        *(f32x4*)(out + base) = ov;
      }
    }
  }
}

extern "C" void kernel_launch(void* const* d_in, const int* in_sizes, int n_in,
                              void* d_out, int out_size, void* d_ws, size_t ws_size,
                              hipStream_t stream) {
  const float* sem   = (const float*)d_in[0];
  const float* foren = (const float*)d_in[1];
  const float* Wq    = (const float*)d_in[2];
  const float* bq    = (const float*)d_in[3];
  const float* Wk    = (const float*)d_in[4];
  const float* bk    = (const float*)d_in[5];
  const float* Wv    = (const float*)d_in[6];
  const float* bv    = (const float*)d_in[7];
  const float* gamma = (const float*)d_in[8];
  float* out = (float*)d_out;

  // ws (u16 units): Wq 16K | Wk 16K | Wv 64K | Q 2M | K 2M | V 8M | qnsq f32 32K | knmax u32 8
  u16* Wqb = (u16*)d_ws;
  u16* Wkb = Wqb + 16384;
  u16* Wvb = Wkb + 16384;
  u16* Q   = Wvb + 65536;
  u16* K   = Q + (size_t)NB * HW * 64;
  u16* V   = K + (size_t)NB * HW * 64;
  float* qnsq = (float*)(V + (size_t)NB * DIM * HW);
  u32* knmax_u = (u32*)(qnsq + (size_t)NB * HW);

  prep_w <<<384, 256, 0, stream>>>(Wq, Wk, Wv, Wqb, knmax_u);
  proj_q <<<512, 256, 0, stream>>>(sem, Wqb, bq, Q, qnsq);
  proj_kv<<<512, 256, 0, stream>>>(foren, Wkb, Wvb, bk, bv, K, V, knmax_u);
  attn3  <<<256, 512, 0, stream>>>(Q, K, V, qnsq, knmax_u, sem, gamma, out);
}